// Round 1
// baseline (599.469 us; speedup 1.0000x reference)
//
#include <hip/hip_runtime.h>
#include <hip/hip_bf16.h>
#include <cstddef>

#define L_SEQ 32768
#define H_FEAT 512
#define P_STATE 256
#define N2 512              // 2*P (re/im interleaved)
#define CS 64               // scan chunk size
#define NCH (L_SEQ / CS)    // 512 chunks

// ---------------------------------------------------------------------------
// Parameter prep: W[2P][H] (real GEMM1 weights), C2[H][2P] (real GEMM2
// weights incl. factor 2 and conj sign), Abar[p] (discretized eigenvalue).
// ---------------------------------------------------------------------------
__global__ __launch_bounds__(256) void param_kernel(
    const float* __restrict__ lr, const float* __restrict__ li,
    const float* __restrict__ b,  const float* __restrict__ c,
    const float* __restrict__ delta,
    float* __restrict__ W, float* __restrict__ C2, float2* __restrict__ Abar)
{
    int tid = blockIdx.x * blockDim.x + threadIdx.x;   // 0 .. P*H-1 (131072)

    // --- W entries: p = tid/H, h = tid%H ---
    {
        int p = tid >> 9;
        int h = tid & 511;
        float step = expf(delta[p]);
        float zr = 0.5f * step * lr[p];
        float zi = 0.5f * step * li[p];
        float dr = 1.0f - zr, di = -zi;
        float den = dr * dr + di * di;
        float blr = dr / den, bli = -di / den;       // BL = 1/(1-z)
        float bbr = blr * step, bbi = bli * step;    // BL*step
        float b0 = b[((size_t)(p * H_FEAT + h)) * 2 + 0];
        float b1 = b[((size_t)(p * H_FEAT + h)) * 2 + 1];
        W[(size_t)(2 * p) * H_FEAT + h]     = bbr * b0 - bbi * b1;  // Re(B_bar)
        W[(size_t)(2 * p + 1) * H_FEAT + h] = bbr * b1 + bbi * b0;  // Im(B_bar)
    }

    // --- C2 entries: h2 = tid/P, p2 = tid%P ---
    {
        int h2 = tid >> 8;
        int p2 = tid & 255;
        float c0 = c[((size_t)(h2 * P_STATE + p2)) * 2 + 0];
        float c1 = c[((size_t)(h2 * P_STATE + p2)) * 2 + 1];
        C2[(size_t)h2 * N2 + 2 * p2]     =  2.0f * c0;
        C2[(size_t)h2 * N2 + 2 * p2 + 1] = -2.0f * c1;
    }

    // --- Abar (first P threads) ---
    if (tid < P_STATE) {
        int p = tid;
        float step = expf(delta[p]);
        float zr = 0.5f * step * lr[p];
        float zi = 0.5f * step * li[p];
        float dr = 1.0f - zr, di = -zi;
        float den = dr * dr + di * di;
        float blr = dr / den, bli = -di / den;
        float nr = 1.0f + zr, ni = zi;
        Abar[p] = make_float2(blr * nr - bli * ni, blr * ni + bli * nr);
    }
}

// ---------------------------------------------------------------------------
// f32 GEMM: C[M][N] = A[M][K] * Bw[N][K]^T  (+ optional dvec[col]*U[row][col])
// BM=BN=128, BK=8, 256 threads, 8x8 per thread.
// M,N,K all multiples of tile sizes here (no bounds checks).
// ---------------------------------------------------------------------------
__global__ __launch_bounds__(256) void gemm128(
    const float* __restrict__ A, const float* __restrict__ Bw,
    float* __restrict__ C, const float* __restrict__ U,
    const float* __restrict__ dvec, int M, int N, int K)
{
    __shared__ float As[8][128];
    __shared__ float Bs[8][128];

    int tid = threadIdx.x;
    int tx = tid & 15, ty = tid >> 4;
    int bm = blockIdx.y * 128, bn = blockIdx.x * 128;

    int lrow = tid >> 1;          // 0..127
    int lcol = (tid & 1) << 2;    // 0 or 4

    const float* Aptr = A + (size_t)(bm + lrow) * K + lcol;
    const float* Bptr = Bw + (size_t)(bn + lrow) * K + lcol;

    float acc[8][8] = {};

    for (int k0 = 0; k0 < K; k0 += 8) {
        float4 av = *(const float4*)(Aptr + k0);
        float4 bv = *(const float4*)(Bptr + k0);
        As[lcol + 0][lrow] = av.x; As[lcol + 1][lrow] = av.y;
        As[lcol + 2][lrow] = av.z; As[lcol + 3][lrow] = av.w;
        Bs[lcol + 0][lrow] = bv.x; Bs[lcol + 1][lrow] = bv.y;
        Bs[lcol + 2][lrow] = bv.z; Bs[lcol + 3][lrow] = bv.w;
        __syncthreads();
#pragma unroll
        for (int k = 0; k < 8; k++) {
            float a[8], bb[8];
#pragma unroll
            for (int i = 0; i < 8; i++) a[i] = As[k][ty * 8 + i];
#pragma unroll
            for (int j = 0; j < 8; j++) bb[j] = Bs[k][tx * 8 + j];
#pragma unroll
            for (int i = 0; i < 8; i++)
#pragma unroll
                for (int j = 0; j < 8; j++)
                    acc[i][j] = fmaf(a[i], bb[j], acc[i][j]);
        }
        __syncthreads();
    }

#pragma unroll
    for (int i = 0; i < 8; i++) {
        int row = bm + ty * 8 + i;
#pragma unroll
        for (int j = 0; j < 8; j++) {
            int col = bn + tx * 8 + j;
            float v = acc[i][j];
            if (U) v += dvec[col] * U[(size_t)row * N + col];
            C[(size_t)row * N + col] = v;
        }
    }
}

// ---------------------------------------------------------------------------
// Scan pass 1: per-(p, chunk) local scan with zero init; write chunk-end.
// Bu layout: float2 Bu2[l * P + p].  ends layout: [p][chunk].
// ---------------------------------------------------------------------------
__global__ __launch_bounds__(256) void scan_pass1(
    const float2* __restrict__ Bu, const float2* __restrict__ Abar,
    float2* __restrict__ ends)
{
    int tid = blockIdx.x * blockDim.x + threadIdx.x;  // 0 .. P*NCH-1
    int chunk = tid >> 8;
    int p = tid & 255;
    float2 A = Abar[p];
    float2 s = make_float2(0.f, 0.f);
    size_t base = (size_t)chunk * CS;
#pragma unroll 4
    for (int i = 0; i < CS; i++) {
        float2 u = Bu[(base + i) * P_STATE + p];
        float sr = fmaf(A.x, s.x, fmaf(-A.y, s.y, u.x));
        float si = fmaf(A.x, s.y, fmaf(A.y, s.x, u.y));
        s = make_float2(sr, si);
    }
    ends[(size_t)p * NCH + chunk] = s;
}

// ---------------------------------------------------------------------------
// Scan pass 2: per-p Kogge-Stone scan across NCH chunk pairs (A^CS, end).
// Writes exclusive carries[p][chunk].
// ---------------------------------------------------------------------------
__global__ __launch_bounds__(512) void scan_pass2(
    const float2* __restrict__ ends, const float2* __restrict__ Abar,
    float2* __restrict__ carries)
{
    __shared__ float2 sA[NCH];
    __shared__ float2 sB[NCH];
    int p = blockIdx.x;
    int t = threadIdx.x;

    float2 a = Abar[p];
    // a^CS, CS=64 -> 6 squarings
#pragma unroll
    for (int i = 0; i < 6; i++) {
        float nr = a.x * a.x - a.y * a.y;
        float ni = 2.f * a.x * a.y;
        a = make_float2(nr, ni);
    }
    float2 A = a;
    float2 bv = ends[(size_t)p * NCH + t];
    sA[t] = A; sB[t] = bv;
    __syncthreads();

    for (int off = 1; off < NCH; off <<= 1) {
        float2 pa, pb;
        bool act = (t >= off);
        if (act) { pa = sA[t - off]; pb = sB[t - off]; }
        __syncthreads();
        if (act) {
            // combine earlier (pa,pb) with later (A,bv)
            float2 nA = make_float2(A.x * pa.x - A.y * pa.y,
                                    A.x * pa.y + A.y * pa.x);
            float2 nB = make_float2(fmaf(A.x, pb.x, fmaf(-A.y, pb.y, bv.x)),
                                    fmaf(A.x, pb.y, fmaf(A.y, pb.x, bv.y)));
            A = nA; bv = nB;
            sA[t] = A; sB[t] = bv;
        }
        __syncthreads();
    }

    float2 carry = (t == 0) ? make_float2(0.f, 0.f) : sB[t - 1];
    carries[(size_t)p * NCH + t] = carry;
}

// ---------------------------------------------------------------------------
// Scan pass 3: re-walk each chunk with the carry, write states in-place.
// ---------------------------------------------------------------------------
__global__ __launch_bounds__(256) void scan_pass3(
    float2* __restrict__ Bu, const float2* __restrict__ Abar,
    const float2* __restrict__ carries)
{
    int tid = blockIdx.x * blockDim.x + threadIdx.x;
    int chunk = tid >> 8;
    int p = tid & 255;
    float2 A = Abar[p];
    float2 s = carries[(size_t)p * NCH + chunk];
    size_t base = (size_t)chunk * CS;
#pragma unroll 4
    for (int i = 0; i < CS; i++) {
        size_t idx = (base + i) * P_STATE + p;
        float2 u = Bu[idx];
        float sr = fmaf(A.x, s.x, fmaf(-A.y, s.y, u.x));
        float si = fmaf(A.x, s.y, fmaf(A.y, s.x, u.y));
        s = make_float2(sr, si);
        Bu[idx] = s;
    }
}

// ---------------------------------------------------------------------------
extern "C" void kernel_launch(void* const* d_in, const int* in_sizes, int n_in,
                              void* d_out, int out_size, void* d_ws, size_t ws_size,
                              hipStream_t stream) {
    const float* u     = (const float*)d_in[0];   // [L][H]
    const float* lr    = (const float*)d_in[1];   // [P]
    const float* li    = (const float*)d_in[2];   // [P]
    const float* b     = (const float*)d_in[3];   // [P][H][2]
    const float* c     = (const float*)d_in[4];   // [H][P][2]
    const float* dvec  = (const float*)d_in[5];   // [H]
    const float* delta = (const float*)d_in[6];   // [P]
    float* out = (float*)d_out;

    // workspace layout (floats)
    float* ws = (float*)d_ws;
    float*  Bu      = ws;                                   // L*N2 = 16777216
    float*  W       = Bu + (size_t)L_SEQ * N2;              // 262144
    float*  C2      = W + (size_t)N2 * H_FEAT;              // 262144
    float2* Abar    = (float2*)(C2 + (size_t)H_FEAT * N2);  // P float2
    float2* ends    = (float2*)((float*)Abar + 2 * P_STATE);        // P*NCH float2
    float2* carries = ends + (size_t)P_STATE * NCH;

    // 1. params
    param_kernel<<<(P_STATE * H_FEAT) / 256, 256, 0, stream>>>(
        lr, li, b, c, delta, W, C2, Abar);

    // 2. GEMM1: Bu[L][N2] = u[L][H] @ W[N2][H]^T
    {
        dim3 grid(N2 / 128, L_SEQ / 128);
        gemm128<<<grid, 256, 0, stream>>>(u, W, Bu, nullptr, nullptr,
                                          L_SEQ, N2, H_FEAT);
    }

    // 3. scan
    scan_pass1<<<(P_STATE * NCH) / 256, 256, 0, stream>>>(
        (const float2*)Bu, Abar, ends);
    scan_pass2<<<P_STATE, NCH, 0, stream>>>(ends, Abar, carries);
    scan_pass3<<<(P_STATE * NCH) / 256, 256, 0, stream>>>(
        (float2*)Bu, Abar, carries);

    // 4. GEMM2: out[L][H] = xs[L][N2] @ C2[H][N2]^T + d*u
    {
        dim3 grid(H_FEAT / 128, L_SEQ / 128);
        gemm128<<<grid, 256, 0, stream>>>(Bu, C2, out, u, dvec,
                                          L_SEQ, H_FEAT, N2);
    }
}

// Round 2
// 281.639 us; speedup vs baseline: 2.1285x; 2.1285x over previous
//
#include <hip/hip_runtime.h>
#include <cstddef>

#define L_SEQ 32768
#define H_FEAT 512
#define P_STATE 256
#define N2 512              // 2*P (re/im interleaved)
#define CS 32               // scan chunk size
#define NCH (L_SEQ / CS)    // 1024 chunks

typedef __bf16 bf16x8 __attribute__((ext_vector_type(8)));
typedef float f32x4 __attribute__((ext_vector_type(4)));

// async global->LDS, 16B per lane; LDS dst must be uniform base + lane*16
#define GLDS16(g, l) __builtin_amdgcn_global_load_lds( \
    (const __attribute__((address_space(1))) void*)(g), \
    (__attribute__((address_space(3))) void*)(l), 16, 0, 0)

__device__ __forceinline__ unsigned bf_rne(float x) {   // bf16 bits (RNE) in low 16
    unsigned u = __float_as_uint(x);
    return (u + 0x7fffu + ((u >> 16) & 1u)) >> 16;
}
__device__ __forceinline__ float bf_f(unsigned bits) {
    return __uint_as_float(bits << 16);
}

// ---------------------------------------------------------------------------
// Params: W split (bf16 hi/lo, [N2][H]), C2 split ([H][N2]), Abar.
// ---------------------------------------------------------------------------
__global__ __launch_bounds__(256) void param_kernel(
    const float* __restrict__ lr, const float* __restrict__ li,
    const float* __restrict__ b,  const float* __restrict__ c,
    const float* __restrict__ delta,
    ushort* __restrict__ W_hi, ushort* __restrict__ W_lo,
    ushort* __restrict__ C2_hi, ushort* __restrict__ C2_lo,
    float2* __restrict__ Abar)
{
    int tid = blockIdx.x * blockDim.x + threadIdx.x;   // 0 .. P*H-1 (131072)

    // --- W rows 2p (Re), 2p+1 (Im): p = tid/H, h = tid%H ---
    {
        int p = tid >> 9;
        int h = tid & 511;
        float step = expf(delta[p]);
        float zr = 0.5f * step * lr[p];
        float zi = 0.5f * step * li[p];
        float dr = 1.0f - zr, di = -zi;
        float den = dr * dr + di * di;
        float blr = dr / den, bli = -di / den;       // BL = 1/(1-z)
        float bbr = blr * step, bbi = bli * step;    // BL*step
        float b0 = b[((size_t)(p * H_FEAT + h)) * 2 + 0];
        float b1 = b[((size_t)(p * H_FEAT + h)) * 2 + 1];
        float vr = bbr * b0 - bbi * b1;              // Re(B_bar)
        float vi = bbr * b1 + bbi * b0;              // Im(B_bar)
        unsigned hr = bf_rne(vr), hl = bf_rne(vr - bf_f(hr));
        unsigned ir = bf_rne(vi), il = bf_rne(vi - bf_f(ir));
        size_t o0 = (size_t)(2 * p) * H_FEAT + h;
        size_t o1 = (size_t)(2 * p + 1) * H_FEAT + h;
        W_hi[o0] = (ushort)hr; W_lo[o0] = (ushort)hl;
        W_hi[o1] = (ushort)ir; W_lo[o1] = (ushort)il;
    }

    // --- C2: h2 = tid/P, p2 = tid%P ---
    {
        int h2 = tid >> 8;
        int p2 = tid & 255;
        float c0 =  2.0f * c[((size_t)(h2 * P_STATE + p2)) * 2 + 0];
        float c1 = -2.0f * c[((size_t)(h2 * P_STATE + p2)) * 2 + 1];
        unsigned h0 = bf_rne(c0), l0 = bf_rne(c0 - bf_f(h0));
        unsigned h1 = bf_rne(c1), l1 = bf_rne(c1 - bf_f(h1));
        size_t o0 = (size_t)h2 * N2 + 2 * p2;
        C2_hi[o0] = (ushort)h0;     C2_lo[o0] = (ushort)l0;
        C2_hi[o0 + 1] = (ushort)h1; C2_lo[o0 + 1] = (ushort)l1;
    }

    // --- Abar ---
    if (tid < P_STATE) {
        int p = tid;
        float step = expf(delta[p]);
        float zr = 0.5f * step * lr[p];
        float zi = 0.5f * step * li[p];
        float dr = 1.0f - zr, di = -zi;
        float den = dr * dr + di * di;
        float blr = dr / den, bli = -di / den;
        float nr = 1.0f + zr, ni = zi;
        Abar[p] = make_float2(blr * nr - bli * ni, blr * ni + bli * nr);
    }
}

// ---------------------------------------------------------------------------
// GEMM1: Bu[M][512] = u[M][512](f32, split in-kernel) @ W[512][512]^T (pre-split)
// 128x128 block, BK=32, 4 waves, each wave 64x64 via 4x4 16x16x32 MFMA frags,
// 3 MFMA per frag (hi*hi + hi*lo + lo*hi).
// ---------------------------------------------------------------------------
__global__ __launch_bounds__(256) void gemm1(
    const float* __restrict__ A,
    const ushort* __restrict__ Bhi, const ushort* __restrict__ Blo,
    float* __restrict__ C)
{
    __shared__ ushort As_hi[128 * 32], As_lo[128 * 32];
    __shared__ ushort Bs_hi[128 * 32], Bs_lo[128 * 32];
    const int tid = threadIdx.x;
    const int ln = tid & 63, wv = tid >> 6;
    const int bm = blockIdx.y * 128, bn = blockIdx.x * 128;
    const int m = ln & 15, q = ln >> 4;
    const int wr = (wv >> 1) * 64, wc = (wv & 1) * 64;
    const int grow = ln >> 2, seg = (ln & 3) * 8;

    f32x4 acc[4][4] = {};

    for (int k0 = 0; k0 < 512; k0 += 32) {
        // --- B tiles (bf16 hi/lo) via async global->LDS, 4 x 1KB per wave ---
#pragma unroll
        for (int s = 0; s < 4; s++) {
            int t = wv * 4 + s;            // 0..15
            int ch = t & 7;
            int row = ch * 16 + grow;
            const ushort* src = (t < 8 ? Bhi : Blo) + (size_t)(bn + row) * 512 + k0 + seg;
            ushort* dst = (t < 8 ? Bs_hi : Bs_lo) + ch * 512 + ln * 8;
            GLDS16(src, dst);
        }
        // --- A tile: f32 load + split to hi/lo bf16 ---
#pragma unroll
        for (int r = 0; r < 4; r++) {
            int idx = tid + r * 256;       // 0..1023
            int row = idx >> 3;
            int c4 = (idx & 7) << 2;
            const float4 v = *(const float4*)(A + (size_t)(bm + row) * 512 + k0 + c4);
            unsigned u0 = __float_as_uint(v.x), u1 = __float_as_uint(v.y);
            unsigned u2 = __float_as_uint(v.z), u3 = __float_as_uint(v.w);
            unsigned hi01 = (u0 >> 16) | (u1 & 0xffff0000u);
            unsigned hi23 = (u2 >> 16) | (u3 & 0xffff0000u);
            float d0 = v.x - __uint_as_float(u0 & 0xffff0000u);
            float d1 = v.y - __uint_as_float(u1 & 0xffff0000u);
            float d2 = v.z - __uint_as_float(u2 & 0xffff0000u);
            float d3 = v.w - __uint_as_float(u3 & 0xffff0000u);
            unsigned lo01 = (__float_as_uint(d0) >> 16) | (__float_as_uint(d1) & 0xffff0000u);
            unsigned lo23 = (__float_as_uint(d2) >> 16) | (__float_as_uint(d3) & 0xffff0000u);
            *(uint2*)(As_hi + row * 32 + c4) = make_uint2(hi01, hi23);
            *(uint2*)(As_lo + row * 32 + c4) = make_uint2(lo01, lo23);
        }
        __syncthreads();

        bf16x8 ah[4], al[4], bh[4], bl[4];
#pragma unroll
        for (int i = 0; i < 4; i++) {
            ah[i] = *(const bf16x8*)(As_hi + (wr + i * 16 + m) * 32 + q * 8);
            al[i] = *(const bf16x8*)(As_lo + (wr + i * 16 + m) * 32 + q * 8);
            bh[i] = *(const bf16x8*)(Bs_hi + (wc + i * 16 + m) * 32 + q * 8);
            bl[i] = *(const bf16x8*)(Bs_lo + (wc + i * 16 + m) * 32 + q * 8);
        }
#pragma unroll
        for (int i = 0; i < 4; i++)
#pragma unroll
            for (int j = 0; j < 4; j++) {
                acc[i][j] = __builtin_amdgcn_mfma_f32_16x16x32_bf16(ah[i], bh[j], acc[i][j], 0, 0, 0);
                acc[i][j] = __builtin_amdgcn_mfma_f32_16x16x32_bf16(ah[i], bl[j], acc[i][j], 0, 0, 0);
                acc[i][j] = __builtin_amdgcn_mfma_f32_16x16x32_bf16(al[i], bh[j], acc[i][j], 0, 0, 0);
            }
        __syncthreads();
    }

#pragma unroll
    for (int i = 0; i < 4; i++)
#pragma unroll
        for (int j = 0; j < 4; j++)
#pragma unroll
            for (int r = 0; r < 4; r++) {
                int row = bm + wr + i * 16 + q * 4 + r;
                int col = bn + wc + j * 16 + m;
                C[(size_t)row * 512 + col] = acc[i][j][r];
            }
}

// ---------------------------------------------------------------------------
// GEMM2: out[M][512] = xs(packed hi/lo)[M][512] @ C2[512][512]^T + d*u
// ---------------------------------------------------------------------------
__global__ __launch_bounds__(256) void gemm2(
    const unsigned* __restrict__ Xp,
    const ushort* __restrict__ Bhi, const ushort* __restrict__ Blo,
    float* __restrict__ Cout, const float* __restrict__ U,
    const float* __restrict__ dvec)
{
    __shared__ ushort As_hi[128 * 32], As_lo[128 * 32];
    __shared__ ushort Bs_hi[128 * 32], Bs_lo[128 * 32];
    const int tid = threadIdx.x;
    const int ln = tid & 63, wv = tid >> 6;
    const int bm = blockIdx.y * 128, bn = blockIdx.x * 128;
    const int m = ln & 15, q = ln >> 4;
    const int wr = (wv >> 1) * 64, wc = (wv & 1) * 64;
    const int grow = ln >> 2, seg = (ln & 3) * 8;

    f32x4 acc[4][4] = {};

    for (int k0 = 0; k0 < 512; k0 += 32) {
#pragma unroll
        for (int s = 0; s < 4; s++) {
            int t = wv * 4 + s;
            int ch = t & 7;
            int row = ch * 16 + grow;
            const ushort* src = (t < 8 ? Bhi : Blo) + (size_t)(bn + row) * 512 + k0 + seg;
            ushort* dst = (t < 8 ? Bs_hi : Bs_lo) + ch * 512 + ln * 8;
            GLDS16(src, dst);
        }
#pragma unroll
        for (int r = 0; r < 4; r++) {
            int idx = tid + r * 256;
            int row = idx >> 3;
            int c4 = (idx & 7) << 2;
            const uint4 v = *(const uint4*)(Xp + (size_t)(bm + row) * 512 + k0 + c4);
            unsigned hi01 = (v.x >> 16) | (v.y & 0xffff0000u);
            unsigned hi23 = (v.z >> 16) | (v.w & 0xffff0000u);
            unsigned lo01 = (v.x & 0xffffu) | (v.y << 16);
            unsigned lo23 = (v.z & 0xffffu) | (v.w << 16);
            *(uint2*)(As_hi + row * 32 + c4) = make_uint2(hi01, hi23);
            *(uint2*)(As_lo + row * 32 + c4) = make_uint2(lo01, lo23);
        }
        __syncthreads();

        bf16x8 ah[4], al[4], bh[4], bl[4];
#pragma unroll
        for (int i = 0; i < 4; i++) {
            ah[i] = *(const bf16x8*)(As_hi + (wr + i * 16 + m) * 32 + q * 8);
            al[i] = *(const bf16x8*)(As_lo + (wr + i * 16 + m) * 32 + q * 8);
            bh[i] = *(const bf16x8*)(Bs_hi + (wc + i * 16 + m) * 32 + q * 8);
            bl[i] = *(const bf16x8*)(Bs_lo + (wc + i * 16 + m) * 32 + q * 8);
        }
#pragma unroll
        for (int i = 0; i < 4; i++)
#pragma unroll
            for (int j = 0; j < 4; j++) {
                acc[i][j] = __builtin_amdgcn_mfma_f32_16x16x32_bf16(ah[i], bh[j], acc[i][j], 0, 0, 0);
                acc[i][j] = __builtin_amdgcn_mfma_f32_16x16x32_bf16(ah[i], bl[j], acc[i][j], 0, 0, 0);
                acc[i][j] = __builtin_amdgcn_mfma_f32_16x16x32_bf16(al[i], bh[j], acc[i][j], 0, 0, 0);
            }
        __syncthreads();
    }

#pragma unroll
    for (int i = 0; i < 4; i++)
#pragma unroll
        for (int j = 0; j < 4; j++) {
            int col = bn + wc + j * 16 + m;
            float dv = dvec[col];
#pragma unroll
            for (int r = 0; r < 4; r++) {
                int row = bm + wr + i * 16 + q * 4 + r;
                Cout[(size_t)row * 512 + col] =
                    acc[i][j][r] + dv * U[(size_t)row * 512 + col];
            }
        }
}

// ---------------------------------------------------------------------------
// Scan pass 1: per-(p, chunk) local scan with zero init; write chunk-end.
// ---------------------------------------------------------------------------
__global__ __launch_bounds__(256) void scan_pass1(
    const float2* __restrict__ Bu, const float2* __restrict__ Abar,
    float2* __restrict__ ends)
{
    int tid = blockIdx.x * blockDim.x + threadIdx.x;  // 0 .. P*NCH-1
    int chunk = tid >> 8;
    int p = tid & 255;
    float2 A = Abar[p];
    float2 s = make_float2(0.f, 0.f);
    size_t base = (size_t)chunk * CS;
#pragma unroll 8
    for (int i = 0; i < CS; i++) {
        float2 u = Bu[(base + i) * P_STATE + p];
        float sr = fmaf(A.x, s.x, fmaf(-A.y, s.y, u.x));
        float si = fmaf(A.x, s.y, fmaf(A.y, s.x, u.y));
        s = make_float2(sr, si);
    }
    ends[(size_t)p * NCH + chunk] = s;
}

// ---------------------------------------------------------------------------
// Scan pass 2: per-p Kogge-Stone over NCH chunk pairs (A^CS, end) -> carries.
// ---------------------------------------------------------------------------
__global__ __launch_bounds__(1024) void scan_pass2(
    const float2* __restrict__ ends, const float2* __restrict__ Abar,
    float2* __restrict__ carries)
{
    __shared__ float2 sA[NCH];
    __shared__ float2 sB[NCH];
    int p = blockIdx.x;
    int t = threadIdx.x;

    float2 a = Abar[p];
#pragma unroll
    for (int i = 0; i < 5; i++) {    // a^32
        float nr = a.x * a.x - a.y * a.y;
        float ni = 2.f * a.x * a.y;
        a = make_float2(nr, ni);
    }
    float2 A = a;
    float2 bv = ends[(size_t)p * NCH + t];
    sA[t] = A; sB[t] = bv;
    __syncthreads();

    for (int off = 1; off < NCH; off <<= 1) {
        float2 pa, pb;
        bool act = (t >= off);
        if (act) { pa = sA[t - off]; pb = sB[t - off]; }
        __syncthreads();
        if (act) {
            float2 nA = make_float2(A.x * pa.x - A.y * pa.y,
                                    A.x * pa.y + A.y * pa.x);
            float2 nB = make_float2(fmaf(A.x, pb.x, fmaf(-A.y, pb.y, bv.x)),
                                    fmaf(A.x, pb.y, fmaf(A.y, pb.x, bv.y)));
            A = nA; bv = nB;
            sA[t] = A; sB[t] = bv;
        }
        __syncthreads();
    }

    float2 carry = (t == 0) ? make_float2(0.f, 0.f) : sB[t - 1];
    carries[(size_t)p * NCH + t] = carry;
}

// ---------------------------------------------------------------------------
// Scan pass 3: re-walk with carry; write packed {bf16_hi,bf16_lo} in-place.
// All accesses through uint2 to avoid type-aliasing reorder.
// ---------------------------------------------------------------------------
__global__ __launch_bounds__(256) void scan_pass3(
    uint2* __restrict__ Xp, const float2* __restrict__ Abar,
    const float2* __restrict__ carries)
{
    int tid = blockIdx.x * blockDim.x + threadIdx.x;
    int chunk = tid >> 8;
    int p = tid & 255;
    float2 A = Abar[p];
    float2 s = carries[(size_t)p * NCH + chunk];
    size_t base = (size_t)chunk * CS;
#pragma unroll 8
    for (int i = 0; i < CS; i++) {
        size_t off = (base + i) * P_STATE + p;
        uint2 ub = Xp[off];
        float ux = __uint_as_float(ub.x);
        float uy = __uint_as_float(ub.y);
        float sr = fmaf(A.x, s.x, fmaf(-A.y, s.y, ux));
        float si = fmaf(A.x, s.y, fmaf(A.y, s.x, uy));
        s = make_float2(sr, si);
        unsigned hr = bf_rne(sr);
        unsigned lr2 = __float_as_uint(sr - bf_f(hr)) >> 16;
        unsigned hi_ = bf_rne(si);
        unsigned li2 = __float_as_uint(si - bf_f(hi_)) >> 16;
        Xp[off] = make_uint2((hr << 16) | lr2, (hi_ << 16) | li2);
    }
}

// ---------------------------------------------------------------------------
extern "C" void kernel_launch(void* const* d_in, const int* in_sizes, int n_in,
                              void* d_out, int out_size, void* d_ws, size_t ws_size,
                              hipStream_t stream) {
    const float* u     = (const float*)d_in[0];   // [L][H]
    const float* lr    = (const float*)d_in[1];   // [P]
    const float* li    = (const float*)d_in[2];   // [P]
    const float* b     = (const float*)d_in[3];   // [P][H][2]
    const float* c     = (const float*)d_in[4];   // [H][P][2]
    const float* dvec  = (const float*)d_in[5];   // [H]
    const float* delta = (const float*)d_in[6];   // [P]
    float* out = (float*)d_out;

    // workspace layout
    char* p = (char*)d_ws;
    float*  Bu      = (float*)p;   p += (size_t)L_SEQ * N2 * 4;        // 64 MiB
    float2* ends    = (float2*)p;  p += (size_t)P_STATE * NCH * 8;     // 2 MiB
    float2* carries = (float2*)p;  p += (size_t)P_STATE * NCH * 8;     // 2 MiB
    ushort* W_hi    = (ushort*)p;  p += (size_t)N2 * H_FEAT * 2;
    ushort* W_lo    = (ushort*)p;  p += (size_t)N2 * H_FEAT * 2;
    ushort* C2_hi   = (ushort*)p;  p += (size_t)H_FEAT * N2 * 2;
    ushort* C2_lo   = (ushort*)p;  p += (size_t)H_FEAT * N2 * 2;
    float2* Abar    = (float2*)p;  p += (size_t)P_STATE * 8;

    // 1. params (+ weight splitting)
    param_kernel<<<(P_STATE * H_FEAT) / 256, 256, 0, stream>>>(
        lr, li, b, c, delta, W_hi, W_lo, C2_hi, C2_lo, Abar);

    // 2. GEMM1: Bu = u @ W^T   (split-bf16 MFMA)
    {
        dim3 grid(N2 / 128, L_SEQ / 128);
        gemm1<<<grid, 256, 0, stream>>>(u, W_hi, W_lo, Bu);
    }

    // 3. scan
    scan_pass1<<<(P_STATE * NCH) / 256, 256, 0, stream>>>(
        (const float2*)Bu, Abar, ends);
    scan_pass2<<<P_STATE, NCH, 0, stream>>>(ends, Abar, carries);
    scan_pass3<<<(P_STATE * NCH) / 256, 256, 0, stream>>>(
        (uint2*)Bu, Abar, carries);

    // 4. GEMM2: out = xs @ C2^T + d*u   (split-bf16 MFMA, packed xs)
    {
        dim3 grid(H_FEAT / 128, L_SEQ / 128);
        gemm2<<<grid, 256, 0, stream>>>((const unsigned*)Bu, C2_hi, C2_lo,
                                        out, u, dvec);
    }
}

// Round 3
// 253.735 us; speedup vs baseline: 2.3626x; 1.1100x over previous
//
#include <hip/hip_runtime.h>
#include <cstddef>

#define L_SEQ 32768
#define H_FEAT 512
#define P_STATE 256
#define N2 512              // 2*P (re/im interleaved)
#define CS 32               // scan chunk size
#define NCH (L_SEQ / CS)    // 1024 chunks

typedef __bf16 bf16x8 __attribute__((ext_vector_type(8)));
typedef float f32x4 __attribute__((ext_vector_type(4)));

// async global->LDS, 16B per lane; LDS dst must be uniform base + lane*16
#define GLDS16(g, l) __builtin_amdgcn_global_load_lds( \
    (const __attribute__((address_space(1))) void*)(g), \
    (__attribute__((address_space(3))) void*)(l), 16, 0, 0)

__device__ __forceinline__ unsigned bf_rne(float x) {   // bf16 bits (RNE) in low 16
    unsigned u = __float_as_uint(x);
    return (u + 0x7fffu + ((u >> 16) & 1u)) >> 16;
}
__device__ __forceinline__ float bf_f(unsigned bits) {
    return __uint_as_float(bits << 16);
}

// ---------------------------------------------------------------------------
// Params: W split (bf16 hi/lo, [N2][H]), C2 split ([H][N2]), Abar.
// ---------------------------------------------------------------------------
__global__ __launch_bounds__(256) void param_kernel(
    const float* __restrict__ lr, const float* __restrict__ li,
    const float* __restrict__ b,  const float* __restrict__ c,
    const float* __restrict__ delta,
    ushort* __restrict__ W_hi, ushort* __restrict__ W_lo,
    ushort* __restrict__ C2_hi, ushort* __restrict__ C2_lo,
    float2* __restrict__ Abar)
{
    int tid = blockIdx.x * blockDim.x + threadIdx.x;   // 0 .. P*H-1 (131072)

    {
        int p = tid >> 9;
        int h = tid & 511;
        float step = expf(delta[p]);
        float zr = 0.5f * step * lr[p];
        float zi = 0.5f * step * li[p];
        float dr = 1.0f - zr, di = -zi;
        float den = dr * dr + di * di;
        float blr = dr / den, bli = -di / den;       // BL = 1/(1-z)
        float bbr = blr * step, bbi = bli * step;    // BL*step
        float b0 = b[((size_t)(p * H_FEAT + h)) * 2 + 0];
        float b1 = b[((size_t)(p * H_FEAT + h)) * 2 + 1];
        float vr = bbr * b0 - bbi * b1;              // Re(B_bar)
        float vi = bbr * b1 + bbi * b0;              // Im(B_bar)
        unsigned hr = bf_rne(vr), hl = bf_rne(vr - bf_f(hr));
        unsigned ir = bf_rne(vi), il = bf_rne(vi - bf_f(ir));
        size_t o0 = (size_t)(2 * p) * H_FEAT + h;
        size_t o1 = (size_t)(2 * p + 1) * H_FEAT + h;
        W_hi[o0] = (ushort)hr; W_lo[o0] = (ushort)hl;
        W_hi[o1] = (ushort)ir; W_lo[o1] = (ushort)il;
    }

    {
        int h2 = tid >> 8;
        int p2 = tid & 255;
        float c0 =  2.0f * c[((size_t)(h2 * P_STATE + p2)) * 2 + 0];
        float c1 = -2.0f * c[((size_t)(h2 * P_STATE + p2)) * 2 + 1];
        unsigned h0 = bf_rne(c0), l0 = bf_rne(c0 - bf_f(h0));
        unsigned h1 = bf_rne(c1), l1 = bf_rne(c1 - bf_f(h1));
        size_t o0 = (size_t)h2 * N2 + 2 * p2;
        C2_hi[o0] = (ushort)h0;     C2_lo[o0] = (ushort)l0;
        C2_hi[o0 + 1] = (ushort)h1; C2_lo[o0 + 1] = (ushort)l1;
    }

    if (tid < P_STATE) {
        int p = tid;
        float step = expf(delta[p]);
        float zr = 0.5f * step * lr[p];
        float zi = 0.5f * step * li[p];
        float dr = 1.0f - zr, di = -zi;
        float den = dr * dr + di * di;
        float blr = dr / den, bli = -di / den;
        float nr = 1.0f + zr, ni = zi;
        Abar[p] = make_float2(blr * nr - bli * ni, blr * ni + bli * nr);
    }
}

// ---------------------------------------------------------------------------
// GEMM1: Bu[M][512] = u[M][512](f32, split during staging) @ W[512][512]^T
// BM=128, BN=256, BK=32, 256 threads (4 waves), wave tile 64x128 (4x8 frags),
// 3 MFMA per frag (hi*hi + lo*hi + hi*lo). grid = (2, 256).
// ---------------------------------------------------------------------------
__global__ __launch_bounds__(256, 2) void gemm1(
    const float* __restrict__ A,
    const ushort* __restrict__ Bhi, const ushort* __restrict__ Blo,
    float* __restrict__ C)
{
    __shared__ ushort As_hi[128 * 32], As_lo[128 * 32];
    __shared__ ushort Bs_hi[256 * 32], Bs_lo[256 * 32];
    const int tid = threadIdx.x;
    const int ln = tid & 63, wv = tid >> 6;
    const int bm = blockIdx.y * 128, bn = blockIdx.x * 256;
    const int m = ln & 15, q = ln >> 4;
    const int wr = (wv >> 1) * 64, wc = (wv & 1) * 128;

    f32x4 acc[4][8] = {};

    for (int k0 = 0; k0 < 512; k0 += 32) {
        // --- B tiles (bf16 hi/lo): 32 wave-chunks of 16 rows, async ---
#pragma unroll
        for (int s = 0; s < 8; s++) {
            int t = wv * 8 + s;            // 0..31
            int ch = t & 15;
            int row = ch * 16 + (ln >> 2);
            const ushort* src = (t < 16 ? Bhi : Blo)
                                + (size_t)(bn + row) * 512 + k0 + (ln & 3) * 8;
            ushort* dst = (t < 16 ? Bs_hi : Bs_lo) + ch * 512 + ln * 8;
            GLDS16(src, dst);
        }
        // --- A tile: f32 load + split to hi/lo bf16 ---
#pragma unroll
        for (int r = 0; r < 4; r++) {
            int idx = tid + r * 256;       // 0..1023
            int row = idx >> 3;
            int c4 = (idx & 7) << 2;
            const float4 v = *(const float4*)(A + (size_t)(bm + row) * 512 + k0 + c4);
            unsigned u0 = __float_as_uint(v.x), u1 = __float_as_uint(v.y);
            unsigned u2 = __float_as_uint(v.z), u3 = __float_as_uint(v.w);
            unsigned hi01 = (u0 >> 16) | (u1 & 0xffff0000u);
            unsigned hi23 = (u2 >> 16) | (u3 & 0xffff0000u);
            float d0 = v.x - __uint_as_float(u0 & 0xffff0000u);
            float d1 = v.y - __uint_as_float(u1 & 0xffff0000u);
            float d2 = v.z - __uint_as_float(u2 & 0xffff0000u);
            float d3 = v.w - __uint_as_float(u3 & 0xffff0000u);
            unsigned lo01 = (__float_as_uint(d0) >> 16) | (__float_as_uint(d1) & 0xffff0000u);
            unsigned lo23 = (__float_as_uint(d2) >> 16) | (__float_as_uint(d3) & 0xffff0000u);
            *(uint2*)(As_hi + row * 32 + c4) = make_uint2(hi01, hi23);
            *(uint2*)(As_lo + row * 32 + c4) = make_uint2(lo01, lo23);
        }
        __syncthreads();

        bf16x8 ah[4], al[4];
#pragma unroll
        for (int i = 0; i < 4; i++) {
            ah[i] = *(const bf16x8*)(As_hi + (wr + i * 16 + m) * 32 + q * 8);
            al[i] = *(const bf16x8*)(As_lo + (wr + i * 16 + m) * 32 + q * 8);
        }
#pragma unroll
        for (int j = 0; j < 8; j++) {
            bf16x8 bh = *(const bf16x8*)(Bs_hi + (wc + j * 16 + m) * 32 + q * 8);
            bf16x8 bl = *(const bf16x8*)(Bs_lo + (wc + j * 16 + m) * 32 + q * 8);
#pragma unroll
            for (int i = 0; i < 4; i++)
                acc[i][j] = __builtin_amdgcn_mfma_f32_16x16x32_bf16(ah[i], bh, acc[i][j], 0, 0, 0);
#pragma unroll
            for (int i = 0; i < 4; i++)
                acc[i][j] = __builtin_amdgcn_mfma_f32_16x16x32_bf16(al[i], bh, acc[i][j], 0, 0, 0);
#pragma unroll
            for (int i = 0; i < 4; i++)
                acc[i][j] = __builtin_amdgcn_mfma_f32_16x16x32_bf16(ah[i], bl, acc[i][j], 0, 0, 0);
        }
        __syncthreads();
    }

#pragma unroll
    for (int i = 0; i < 4; i++)
#pragma unroll
        for (int j = 0; j < 8; j++)
#pragma unroll
            for (int r = 0; r < 4; r++) {
                int row = bm + wr + i * 16 + q * 4 + r;
                int col = bn + wc + j * 16 + m;
                C[(size_t)row * 512 + col] = acc[i][j][r];
            }
}

// ---------------------------------------------------------------------------
// GEMM2: out[M][512] = xs(packed hi/lo)[M][512] @ C2[512][512]^T + d*u
// Same block structure as gemm1.
// ---------------------------------------------------------------------------
__global__ __launch_bounds__(256, 2) void gemm2(
    const unsigned* __restrict__ Xp,
    const ushort* __restrict__ Bhi, const ushort* __restrict__ Blo,
    float* __restrict__ Cout, const float* __restrict__ U,
    const float* __restrict__ dvec)
{
    __shared__ ushort As_hi[128 * 32], As_lo[128 * 32];
    __shared__ ushort Bs_hi[256 * 32], Bs_lo[256 * 32];
    const int tid = threadIdx.x;
    const int ln = tid & 63, wv = tid >> 6;
    const int bm = blockIdx.y * 128, bn = blockIdx.x * 256;
    const int m = ln & 15, q = ln >> 4;
    const int wr = (wv >> 1) * 64, wc = (wv & 1) * 128;

    f32x4 acc[4][8] = {};

    for (int k0 = 0; k0 < 512; k0 += 32) {
#pragma unroll
        for (int s = 0; s < 8; s++) {
            int t = wv * 8 + s;
            int ch = t & 15;
            int row = ch * 16 + (ln >> 2);
            const ushort* src = (t < 16 ? Bhi : Blo)
                                + (size_t)(bn + row) * 512 + k0 + (ln & 3) * 8;
            ushort* dst = (t < 16 ? Bs_hi : Bs_lo) + ch * 512 + ln * 8;
            GLDS16(src, dst);
        }
#pragma unroll
        for (int r = 0; r < 4; r++) {
            int idx = tid + r * 256;
            int row = idx >> 3;
            int c4 = (idx & 7) << 2;
            const uint4 v = *(const uint4*)(Xp + (size_t)(bm + row) * 512 + k0 + c4);
            unsigned hi01 = (v.x >> 16) | (v.y & 0xffff0000u);
            unsigned hi23 = (v.z >> 16) | (v.w & 0xffff0000u);
            unsigned lo01 = (v.x & 0xffffu) | (v.y << 16);
            unsigned lo23 = (v.z & 0xffffu) | (v.w << 16);
            *(uint2*)(As_hi + row * 32 + c4) = make_uint2(hi01, hi23);
            *(uint2*)(As_lo + row * 32 + c4) = make_uint2(lo01, lo23);
        }
        __syncthreads();

        bf16x8 ah[4], al[4];
#pragma unroll
        for (int i = 0; i < 4; i++) {
            ah[i] = *(const bf16x8*)(As_hi + (wr + i * 16 + m) * 32 + q * 8);
            al[i] = *(const bf16x8*)(As_lo + (wr + i * 16 + m) * 32 + q * 8);
        }
#pragma unroll
        for (int j = 0; j < 8; j++) {
            bf16x8 bh = *(const bf16x8*)(Bs_hi + (wc + j * 16 + m) * 32 + q * 8);
            bf16x8 bl = *(const bf16x8*)(Bs_lo + (wc + j * 16 + m) * 32 + q * 8);
#pragma unroll
            for (int i = 0; i < 4; i++)
                acc[i][j] = __builtin_amdgcn_mfma_f32_16x16x32_bf16(ah[i], bh, acc[i][j], 0, 0, 0);
#pragma unroll
            for (int i = 0; i < 4; i++)
                acc[i][j] = __builtin_amdgcn_mfma_f32_16x16x32_bf16(al[i], bh, acc[i][j], 0, 0, 0);
#pragma unroll
            for (int i = 0; i < 4; i++)
                acc[i][j] = __builtin_amdgcn_mfma_f32_16x16x32_bf16(ah[i], bl, acc[i][j], 0, 0, 0);
        }
        __syncthreads();
    }

#pragma unroll
    for (int i = 0; i < 4; i++)
#pragma unroll
        for (int j = 0; j < 8; j++) {
            int col = bn + wc + j * 16 + m;
            float dv = dvec[col];
#pragma unroll
            for (int r = 0; r < 4; r++) {
                int row = bm + wr + i * 16 + q * 4 + r;
                Cout[(size_t)row * 512 + col] =
                    acc[i][j][r] + dv * U[(size_t)row * 512 + col];
            }
        }
}

// ---------------------------------------------------------------------------
// Scan pass 1: per-(p, chunk) local scan with zero init; write chunk-end.
// ---------------------------------------------------------------------------
__global__ __launch_bounds__(256) void scan_pass1(
    const float2* __restrict__ Bu, const float2* __restrict__ Abar,
    float2* __restrict__ ends)
{
    int tid = blockIdx.x * blockDim.x + threadIdx.x;  // 0 .. P*NCH-1
    int chunk = tid >> 8;
    int p = tid & 255;
    float2 A = Abar[p];
    float2 s = make_float2(0.f, 0.f);
    size_t base = (size_t)chunk * CS;
#pragma unroll 8
    for (int i = 0; i < CS; i++) {
        float2 u = Bu[(base + i) * P_STATE + p];
        float sr = fmaf(A.x, s.x, fmaf(-A.y, s.y, u.x));
        float si = fmaf(A.x, s.y, fmaf(A.y, s.x, u.y));
        s = make_float2(sr, si);
    }
    ends[(size_t)p * NCH + chunk] = s;
}

// ---------------------------------------------------------------------------
// Scan pass 2: per-p Kogge-Stone over NCH chunk pairs (A^CS, end) -> carries.
// ---------------------------------------------------------------------------
__global__ __launch_bounds__(1024) void scan_pass2(
    const float2* __restrict__ ends, const float2* __restrict__ Abar,
    float2* __restrict__ carries)
{
    __shared__ float2 sA[NCH];
    __shared__ float2 sB[NCH];
    int p = blockIdx.x;
    int t = threadIdx.x;

    float2 a = Abar[p];
#pragma unroll
    for (int i = 0; i < 5; i++) {    // a^32
        float nr = a.x * a.x - a.y * a.y;
        float ni = 2.f * a.x * a.y;
        a = make_float2(nr, ni);
    }
    float2 A = a;
    float2 bv = ends[(size_t)p * NCH + t];
    sA[t] = A; sB[t] = bv;
    __syncthreads();

    for (int off = 1; off < NCH; off <<= 1) {
        float2 pa, pb;
        bool act = (t >= off);
        if (act) { pa = sA[t - off]; pb = sB[t - off]; }
        __syncthreads();
        if (act) {
            float2 nA = make_float2(A.x * pa.x - A.y * pa.y,
                                    A.x * pa.y + A.y * pa.x);
            float2 nB = make_float2(fmaf(A.x, pb.x, fmaf(-A.y, pb.y, bv.x)),
                                    fmaf(A.x, pb.y, fmaf(A.y, pb.x, bv.y)));
            A = nA; bv = nB;
            sA[t] = A; sB[t] = bv;
        }
        __syncthreads();
    }

    float2 carry = (t == 0) ? make_float2(0.f, 0.f) : sB[t - 1];
    carries[(size_t)p * NCH + t] = carry;
}

// ---------------------------------------------------------------------------
// Scan pass 3: re-walk with carry; write packed {bf16_hi,bf16_lo} in-place.
// ---------------------------------------------------------------------------
__global__ __launch_bounds__(256) void scan_pass3(
    uint2* __restrict__ Xp, const float2* __restrict__ Abar,
    const float2* __restrict__ carries)
{
    int tid = blockIdx.x * blockDim.x + threadIdx.x;
    int chunk = tid >> 8;
    int p = tid & 255;
    float2 A = Abar[p];
    float2 s = carries[(size_t)p * NCH + chunk];
    size_t base = (size_t)chunk * CS;
#pragma unroll 8
    for (int i = 0; i < CS; i++) {
        size_t off = (base + i) * P_STATE + p;
        uint2 ub = Xp[off];
        float ux = __uint_as_float(ub.x);
        float uy = __uint_as_float(ub.y);
        float sr = fmaf(A.x, s.x, fmaf(-A.y, s.y, ux));
        float si = fmaf(A.x, s.y, fmaf(A.y, s.x, uy));
        s = make_float2(sr, si);
        unsigned hr = bf_rne(sr);
        unsigned lr2 = __float_as_uint(sr - bf_f(hr)) >> 16;
        unsigned hi_ = bf_rne(si);
        unsigned li2 = __float_as_uint(si - bf_f(hi_)) >> 16;
        Xp[off] = make_uint2((hr << 16) | lr2, (hi_ << 16) | li2);
    }
}

// ---------------------------------------------------------------------------
extern "C" void kernel_launch(void* const* d_in, const int* in_sizes, int n_in,
                              void* d_out, int out_size, void* d_ws, size_t ws_size,
                              hipStream_t stream) {
    const float* u     = (const float*)d_in[0];   // [L][H]
    const float* lr    = (const float*)d_in[1];   // [P]
    const float* li    = (const float*)d_in[2];   // [P]
    const float* b     = (const float*)d_in[3];   // [P][H][2]
    const float* c     = (const float*)d_in[4];   // [H][P][2]
    const float* dvec  = (const float*)d_in[5];   // [H]
    const float* delta = (const float*)d_in[6];   // [P]
    float* out = (float*)d_out;

    // workspace layout
    char* p = (char*)d_ws;
    float*  Bu      = (float*)p;   p += (size_t)L_SEQ * N2 * 4;        // 64 MiB
    float2* ends    = (float2*)p;  p += (size_t)P_STATE * NCH * 8;     // 2 MiB
    float2* carries = (float2*)p;  p += (size_t)P_STATE * NCH * 8;     // 2 MiB
    ushort* W_hi    = (ushort*)p;  p += (size_t)N2 * H_FEAT * 2;
    ushort* W_lo    = (ushort*)p;  p += (size_t)N2 * H_FEAT * 2;
    ushort* C2_hi   = (ushort*)p;  p += (size_t)H_FEAT * N2 * 2;
    ushort* C2_lo   = (ushort*)p;  p += (size_t)H_FEAT * N2 * 2;
    float2* Abar    = (float2*)p;  p += (size_t)P_STATE * 8;

    // 1. params (+ weight splitting)
    param_kernel<<<(P_STATE * H_FEAT) / 256, 256, 0, stream>>>(
        lr, li, b, c, delta, W_hi, W_lo, C2_hi, C2_lo, Abar);

    // 2. GEMM1: Bu = u @ W^T   (split-bf16 MFMA)
    {
        dim3 grid(N2 / 256, L_SEQ / 128);
        gemm1<<<grid, 256, 0, stream>>>(u, W_hi, W_lo, Bu);
    }

    // 3. scan
    scan_pass1<<<(P_STATE * NCH) / 256, 256, 0, stream>>>(
        (const float2*)Bu, Abar, ends);
    scan_pass2<<<P_STATE, NCH, 0, stream>>>(ends, Abar, carries);
    scan_pass3<<<(P_STATE * NCH) / 256, 256, 0, stream>>>(
        (uint2*)Bu, Abar, carries);

    // 4. GEMM2: out = xs @ C2^T + d*u   (split-bf16 MFMA, packed xs)
    {
        dim3 grid(H_FEAT / 256, L_SEQ / 128);
        gemm2<<<grid, 256, 0, stream>>>((const unsigned*)Bu, C2_hi, C2_lo,
                                        out, u, dvec);
    }
}